// Round 5
// baseline (118.891 us; speedup 1.0000x reference)
//
#include <hip/hip_runtime.h>

// CRF forward logZ. Inputs: words i32 [2048][256], ThetaB f32 [64][128],
// WA f32 [64][64], E f32 [50002][128]. out: f32 [2048].
// ws: Bt table in bf16, [50002][64] = 6.4 MB, row layout [w][q][kc].
//
// R10: emis_mfma pipelined with asm-volatile loads + counted vmcnt (the R9
//      technique, ported). R9 arithmetic showed emis at ~6800 cy/tile = 8
//      serial HBM latencies: hipcc sank each E-row load to its pack8 use
//      point (occupancy-targeted regalloc), exactly crf's old disease.
//      Now: 3 tile-buffers (8x dwordx4 each) in flight, refill during
//      compute, stores as 2x16B asm (counted), row-clamp instead of guard
//      so wave-uniform waits never diverge. crf_fwdbwd unchanged from R9.

#define NROWS 50002
#define EOS_T 62
#define BOS_T 63
#define TLEN  256
#define LOG64 4.1588830833596715f

typedef __attribute__((ext_vector_type(4))) short bf16x4;
typedef __attribute__((ext_vector_type(8))) short bf16x8;
typedef __attribute__((ext_vector_type(4))) float f32x4;
typedef __attribute__((ext_vector_type(4))) unsigned int u32x4;

// round-half-up f32->bf16 pair pack (2 add + 1 perm); lo in low 16 bits
static __device__ __forceinline__ unsigned pack_bf2(float lo, float hi) {
    unsigned a = __float_as_uint(lo) + 0x8000u;
    unsigned b = __float_as_uint(hi) + 0x8000u;
    return __builtin_amdgcn_perm(b, a, 0x07060302u);
}
static __device__ __forceinline__ bf16x8 pack8(float4 a, float4 b) {
    union { bf16x8 v; unsigned u[4]; } r;
    r.u[0] = pack_bf2(a.x, a.y); r.u[1] = pack_bf2(a.z, a.w);
    r.u[2] = pack_bf2(b.x, b.y); r.u[3] = pack_bf2(b.z, b.w);
    return r.v;
}
static __device__ __forceinline__ bf16x4 pack4(float f0, float f1, float f2, float f3) {
    union { bf16x4 v; unsigned u[2]; } r;
    r.u[0] = pack_bf2(f0, f1); r.u[1] = pack_bf2(f2, f3);
    return r.v;
}

// one Btb row slice for this lane: 32 contiguous bytes = 2x dwordx4 (crf).
#define GLOAD2(buf, addr)                                                     \
    asm volatile("global_load_dwordx4 %0, %2, off\n\t"                        \
                 "global_load_dwordx4 %1, %2, off offset:16"                  \
                 : "=&v"(buf[0]), "=&v"(buf[1]) : "v"(addr))
#define WLOAD(wd, addr)                                                       \
    asm volatile("global_load_dword %0, %1, off" : "=&v"(wd) : "v"(addr))
#define SWAIT(n)                                                              \
    do { __builtin_amdgcn_sched_barrier(0);                                   \
         asm volatile("s_waitcnt vmcnt(" #n ")");                             \
         __builtin_amdgcn_sched_barrier(0); } while (0)

// one E-row slice for this lane: 4x 32B spans (kc*128 + q-slice), 8x dwordx4.
#define GLOADE(buf, addr)                                                     \
    asm volatile("global_load_dwordx4 %0, %8, off\n\t"                        \
                 "global_load_dwordx4 %1, %8, off offset:16\n\t"              \
                 "global_load_dwordx4 %2, %8, off offset:128\n\t"             \
                 "global_load_dwordx4 %3, %8, off offset:144\n\t"             \
                 "global_load_dwordx4 %4, %8, off offset:256\n\t"             \
                 "global_load_dwordx4 %5, %8, off offset:272\n\t"             \
                 "global_load_dwordx4 %6, %8, off offset:384\n\t"             \
                 "global_load_dwordx4 %7, %8, off offset:400"                 \
                 : "=&v"(buf[0]), "=&v"(buf[1]), "=&v"(buf[2]), "=&v"(buf[3]),\
                   "=&v"(buf[4]), "=&v"(buf[5]), "=&v"(buf[6]), "=&v"(buf[7]) \
                 : "v"(addr))
#define GSTORE2(addr, o0, o1)                                                 \
    asm volatile("global_store_dwordx4 %0, %1, off\n\t"                       \
                 "global_store_dwordx4 %0, %2, off offset:16"                 \
                 :: "v"(addr), "v"(o0), "v"(o1) : "memory")

// ---------------------------------------------------------------------------
// Kernel 1: Btb[w][q*4+kc] = bf16(exp(ThetaB[tag].E[w])); tags 62,63 -> 0.
// MFMA GEMM, D[tag = mt*16+q*4+r][word = l]. A = ThetaB (64 VGPR, amortized
// over 4 word-tiles). E tiles stream through 3 asm-load buffers in flight;
// counted vmcnt waits 16/18/12/6 (in-order retirement, stores accounted).
// ---------------------------------------------------------------------------
__global__ __launch_bounds__(64, 1) void emis_mfma(
    const float* __restrict__ ThetaB, const float* __restrict__ E,
    uint2* __restrict__ Btb)
{
    const int l = threadIdx.x & 15;
    const int q = threadIdx.x >> 4;

    // A-frags: A[m=l -> tag mt*16+l][k = q*8+j+32kc] = ThetaB[tag][k]
    bf16x8 Af[4][4];
#pragma unroll
    for (int mt = 0; mt < 4; ++mt)
#pragma unroll
        for (int kc = 0; kc < 4; ++kc) {
            const float4* tp = (const float4*)ThetaB + (mt * 16 + l) * 32 + kc * 8 + q * 2;
            Af[mt][kc] = pack8(tp[0], tp[1]);
        }

    const int base0 = blockIdx.x * 64;
    unsigned long long ea[4], sa[4];
#pragma unroll
    for (int it = 0; it < 4; ++it) {
        int row  = base0 + it * 16 + l;
        int rowc = row < NROWS ? row : NROWS - 1;       // clamped rows write
        ea[it] = (unsigned long long)(const char*)E   + (unsigned long long)rowc * 512u + (unsigned)(q * 32);
        sa[it] = (unsigned long long)(char*)Btb       + (unsigned long long)rowc * 128u + (unsigned)(q * 32);
    }

    // drain compiler-issued vmem (Af loads) so manual counts are exact
    asm volatile("s_waitcnt vmcnt(0) lgkmcnt(0)");
    __builtin_amdgcn_sched_barrier(0);

    u32x4 b0[8], b1[8], b2[8];
    GLOADE(b0, ea[0]); GLOADE(b1, ea[1]); GLOADE(b2, ea[2]);   // 24 in flight

    // compute tile from buf; optionally refill buf for a later tile first
    auto ctile = [&](u32x4 (&buf)[8], unsigned long long saddr, int refill,
                     unsigned long long raddr) {
        bf16x8 Bf[4];
#pragma unroll
        for (int kc = 0; kc < 4; ++kc)
            Bf[kc] = pack8(*(const float4*)&buf[kc * 2], *(const float4*)&buf[kc * 2 + 1]);
        if (refill) GLOADE(buf, raddr);          // buf consumed; reload for T3
        f32x4 D[4];
#pragma unroll
        for (int mt = 0; mt < 4; ++mt) { f32x4 z = {0.f, 0.f, 0.f, 0.f}; D[mt] = z; }
#pragma unroll
        for (int kc = 0; kc < 4; ++kc)
#pragma unroll
            for (int mt = 0; mt < 4; ++mt)
                D[mt] = __builtin_amdgcn_mfma_f32_16x16x32_bf16(Af[mt][kc], Bf[kc], D[mt], 0, 0, 0);
        u32x4 o0, o1;
#pragma unroll
        for (int mt = 0; mt < 4; ++mt) {
            float v0 = expf(D[mt][0]), v1 = expf(D[mt][1]);
            float v2 = expf(D[mt][2]), v3 = expf(D[mt][3]);
            if (mt == 3 && q == 3) { v2 = 0.f; v3 = 0.f; }     // tags 62, 63
            unsigned px = pack_bf2(v0, v1), py = pack_bf2(v2, v3);
            if (mt < 2) { o0[mt * 2] = px; o0[mt * 2 + 1] = py; }
            else        { o1[(mt - 2) * 2] = px; o1[(mt - 2) * 2 + 1] = py; }
        }
        GSTORE2(saddr, o0, o1);
    };

    SWAIT(16);                       // T0 ready (L1,L2 remain)
    ctile(b0, sa[0], 1, ea[3]);      // + refill L3, store S0  -> 26 out
    SWAIT(18);                       // retire L1; L2+L3+S0=18
    ctile(b1, sa[1], 0, 0);          // store S1 -> 20
    SWAIT(12);                       // retire L2; L3+S0+S1=12
    ctile(b2, sa[2], 0, 0);          // store S2 -> 14
    SWAIT(6);                        // retire L3; S0+S1+S2=6
    ctile(b0, sa[3], 0, 0);          // T3, store S3
}

// ---------------------------------------------------------------------------
// Kernel 2: fwd/bwd recurrence, fully in registers.  (unchanged from R9)
// State X = B-operand: X[tag = kc*16+q*4+j][sent = l], bf16x4 per kc.
// fwd (wv=0): A = S^T (mask on m), X' = (S^T X) o e_t, t = 2..127.
// bwd (wv=1): A = S   (mask on k), X' = e_t o (S X),  t = 253..128.
// Emission ring: 9 asm-load groups of 3 VMEM (2x dwordx4 gather + 1 word,
// word fetched 18 steps ahead); per-substep wait = constant vmcnt(24).
// Join: z = (S^T alpha_127) . (e_128 o q_129) via one LDS tile + dot.
// ---------------------------------------------------------------------------
__global__ __launch_bounds__(128, 1) void crf_fwdbwd(
    const int* __restrict__ words, const float* __restrict__ WA,
    const uint2* __restrict__ Btb, float* __restrict__ out)
{
    __shared__ float ytile[16 * 68];
    const int lane  = threadIdx.x & 63;
    const int wv    = threadIdx.x >> 6;          // 0 = fwd, 1 = bwd
    const int l     = lane & 15;
    const int q     = lane >> 4;
    const int sbase = blockIdx.x * 16;

    // Transition A-frags. S[i][j] = exp(WA[i][j]) * (j != BOS)/64.
    bf16x4 Sf[4][4];
#pragma unroll
    for (int mt = 0; mt < 4; ++mt)
#pragma unroll
        for (int kc = 0; kc < 4; ++kc) {
            float t[4];
#pragma unroll
            for (int j = 0; j < 4; ++j) {
                const int mg = mt * 16 + l;          // m index
                const int kg = kc * 16 + q * 4 + j;  // k index
                const int ii = wv ? mg : kg;         // WA row
                const int jj = wv ? kg : mg;         // WA col (masked: S's j)
                t[j] = (jj == BOS_T) ? 0.f : expf(WA[ii * 64 + jj]) * 0.015625f;
            }
            Sf[mt][kc] = pack4(t[0], t[1], t[2], t[3]);
        }

    // Init vector in X-layout, tag jt = kc*16 + q*4 + e:
    // fwd: S[BOS][jt] (alpha_1 pre-emission); bwd: S[jt][EOS] (q_255).
    float g[4][4];
#pragma unroll
    for (int kc = 0; kc < 4; ++kc)
#pragma unroll
        for (int e = 0; e < 4; ++e) {
            const int jt = kc * 16 + q * 4 + e;
            g[kc][e] = wv ? expf(WA[jt * 64 + EOS_T]) * 0.015625f
                          : ((jt == BOS_T) ? 0.f : expf(WA[BOS_T * 64 + jt]) * 0.015625f);
        }

    const int wb   = (sbase + l) * TLEN;
    const int tdir = wv ? -1 : 1;
    const int t0   = wv ? 254 : 1;

    // lane's 32B slice of a Btb row starts at byte q*32
    const unsigned long long btbp   = (unsigned long long)(const char*)Btb + (unsigned)(q * 32);
    const int*               wordsp = words + wb;

    // -------- prologue: 10 words via normal loads, then asm-issue region ----
    const int w0 = wordsp[t0];
    const int w1 = wordsp[t0 + 1 * tdir], w2 = wordsp[t0 + 2 * tdir];
    const int w3 = wordsp[t0 + 3 * tdir], w4 = wordsp[t0 + 4 * tdir];
    const int w5 = wordsp[t0 + 5 * tdir], w6 = wordsp[t0 + 6 * tdir];
    const int w7 = wordsp[t0 + 7 * tdir], w8 = wordsp[t0 + 8 * tdir];
    const int w9 = wordsp[t0 + 9 * tdir];

    unsigned long long aI0 = btbp + (unsigned long long)w0 * 128u;
    unsigned long long aA = btbp + (unsigned long long)w1 * 128u;
    unsigned long long aB = btbp + (unsigned long long)w2 * 128u;
    unsigned long long aC = btbp + (unsigned long long)w3 * 128u;
    unsigned long long aD = btbp + (unsigned long long)w4 * 128u;
    unsigned long long aE = btbp + (unsigned long long)w5 * 128u;
    unsigned long long aF = btbp + (unsigned long long)w6 * 128u;
    unsigned long long aG = btbp + (unsigned long long)w7 * 128u;
    unsigned long long aH = btbp + (unsigned long long)w8 * 128u;
    unsigned long long aJ = btbp + (unsigned long long)w9 * 128u;

    // drain ALL compiler-issued vmem so manual vmcnt counts are exact
    asm volatile("s_waitcnt vmcnt(0) lgkmcnt(0)");
    __builtin_amdgcn_sched_barrier(0);

    u32x4 ei[2], ebA[2], ebB[2], ebC[2], ebD[2], ebE[2], ebF[2], ebG[2], ebH[2], ebI[2];
    int wdA, wdB, wdC, wdD, wdE, wdF, wdG, wdH, wdI;
    // issue groups: [ei:2], then 9x [2 gathers + 1 word] = 29 ops
    GLOAD2(ei, aI0);
    GLOAD2(ebA, aA); WLOAD(wdA, (unsigned long long)(wordsp + t0 + 10 * tdir));
    GLOAD2(ebB, aB); WLOAD(wdB, (unsigned long long)(wordsp + t0 + 11 * tdir));
    GLOAD2(ebC, aC); WLOAD(wdC, (unsigned long long)(wordsp + t0 + 12 * tdir));
    GLOAD2(ebD, aD); WLOAD(wdD, (unsigned long long)(wordsp + t0 + 13 * tdir));
    GLOAD2(ebE, aE); WLOAD(wdE, (unsigned long long)(wordsp + t0 + 14 * tdir));
    GLOAD2(ebF, aF); WLOAD(wdF, (unsigned long long)(wordsp + t0 + 15 * tdir));
    GLOAD2(ebG, aG); WLOAD(wdG, (unsigned long long)(wordsp + t0 + 16 * tdir));
    GLOAD2(ebH, aH); WLOAD(wdH, (unsigned long long)(wordsp + t0 + 17 * tdir));
    GLOAD2(ebI, aJ); WLOAD(wdI, (unsigned long long)(wordsp + t0 + 18 * tdir));

    SWAIT(27);                                   // ei (oldest 2) complete

    // X init = g o e_{t0}   (entry kc at ei[kc>>1], words (kc&1)*2, +1)
    bf16x4 X[4];
#pragma unroll
    for (int kc = 0; kc < 4; ++kc) {
        unsigned ex = ei[kc >> 1][(kc & 1) * 2];
        unsigned ey = ei[kc >> 1][(kc & 1) * 2 + 1];
        float f0 = __uint_as_float(ex << 16)         * g[kc][0];
        float f1 = __uint_as_float(ex & 0xffff0000u) * g[kc][1];
        float f2 = __uint_as_float(ey << 16)         * g[kc][2];
        float f3 = __uint_as_float(ey & 0xffff0000u) * g[kc][3];
        X[kc] = pack4(f0, f1, f2, f3);
    }

    float xf[4][4];                              // last step's f32 products

    // substep for step s: MFMA (regs only) BEFORE the wait; then drain the
    // 9-back group (this step's emission + this refill's word), consume,
    // refill emission for s+9, fetch word for s+18. Exactly 3 asm VMEM.
    auto substep = [&](u32x4 (&eb)[2], int& wd, int widx) {
        f32x4 D[4];
#pragma unroll
        for (int mt = 0; mt < 4; ++mt) { f32x4 z = {0.f, 0.f, 0.f, 0.f}; D[mt] = z; }
#pragma unroll
        for (int kc = 0; kc < 4; ++kc)
#pragma unroll
            for (int mt = 0; mt < 4; ++mt)
                D[mt] = __builtin_amdgcn_mfma_f32_16x16x16bf16_1k(Sf[mt][kc], X[kc], D[mt], 0, 0, 0);
        SWAIT(24);                               // 9-back group (2G+1W) done
#pragma unroll
        for (int kc = 0; kc < 4; ++kc) {
            unsigned ex = eb[kc >> 1][(kc & 1) * 2];
            unsigned ey = eb[kc >> 1][(kc & 1) * 2 + 1];
            float f0 = __uint_as_float(ex << 16);
            float f1 = __uint_as_float(ex & 0xffff0000u);
            float f2 = __uint_as_float(ey << 16);
            float f3 = __uint_as_float(ey & 0xffff0000u);
            xf[kc][0] = D[kc][0] * f0;  xf[kc][1] = D[kc][1] * f1;
            xf[kc][2] = D[kc][2] * f2;  xf[kc][3] = D[kc][3] * f3;
            X[kc] = pack4(xf[kc][0], xf[kc][1], xf[kc][2], xf[kc][3]);
        }
        unsigned long long a = btbp + (unsigned long long)wd * 128u;
        GLOAD2(eb, a);
        WLOAD(wd, (unsigned long long)(wordsp + widx));
    };

    // 126 steps = 14 x 9; word index bounds: fwd max 1+144=145<256,
    // bwd min 254-144=110>=0.
    for (int i = 0; i < 126; i += 9) {
        substep(ebA, wdA, t0 + tdir * (i + 19));
        substep(ebB, wdB, t0 + tdir * (i + 20));
        substep(ebC, wdC, t0 + tdir * (i + 21));
        substep(ebD, wdD, t0 + tdir * (i + 22));
        substep(ebE, wdE, t0 + tdir * (i + 23));
        substep(ebF, wdF, t0 + tdir * (i + 24));
        substep(ebG, wdG, t0 + tdir * (i + 25));
        substep(ebH, wdH, t0 + tdir * (i + 26));
        substep(ebI, wdI, t0 + tdir * (i + 27));
    }

    if (wv == 0) {
        // extra step: Y = S^T alpha_127 (no emission) -> LDS
        f32x4 D[4];
#pragma unroll
        for (int mt = 0; mt < 4; ++mt) { f32x4 z = {0.f, 0.f, 0.f, 0.f}; D[mt] = z; }
#pragma unroll
        for (int kc = 0; kc < 4; ++kc)
#pragma unroll
            for (int mt = 0; mt < 4; ++mt)
                D[mt] = __builtin_amdgcn_mfma_f32_16x16x16bf16_1k(Sf[mt][kc], X[kc], D[mt], 0, 0, 0);
#pragma unroll
        for (int mt = 0; mt < 4; ++mt) {
            float4 o = {D[mt][0], D[mt][1], D[mt][2], D[mt][3]};
            *(float4*)&ytile[l * 68 + mt * 16 + q * 4] = o;
        }
    }
    __syncthreads();
    if (wv == 1) {
        // z[s] = sum_tag Y[tag][s] * X128[tag][s]
        float p = 0.f;
#pragma unroll
        for (int mt = 0; mt < 4; ++mt)
#pragma unroll
            for (int r = 0; r < 4; ++r)
                p = fmaf(ytile[l * 68 + mt * 16 + q * 4 + r], xf[mt][r], p);
        p += __shfl_xor(p, 16, 64);
        p += __shfl_xor(p, 32, 64);
        if (lane < 16)
            out[sbase + l] = logf(p) + 255.0f * LOG64;
    }
}

extern "C" void kernel_launch(void* const* d_in, const int* in_sizes, int n_in,
                              void* d_out, int out_size, void* d_ws, size_t ws_size,
                              hipStream_t stream) {
    const int*   words  = (const int*)d_in[0];
    const float* ThetaB = (const float*)d_in[1];
    const float* WA     = (const float*)d_in[2];
    const float* E      = (const float*)d_in[3];
    float*       outp   = (float*)d_out;
    uint2*       Btb    = (uint2*)d_ws;          // 50002*128 B = 6.4 MB

    // 782 blocks x 1 wave x 4 word-tiles = 50048 >= 50002 rows
    emis_mfma<<<dim3(782), dim3(64), 0, stream>>>(ThetaB, E, Btb);
    // 128 blocks x (fwd wave + bwd wave), 16 sentences each
    crf_fwdbwd<<<dim3(128), dim3(128), 0, stream>>>(words, WA, Btb, outp);
}